// Round 1
// baseline (144.147 us; speedup 1.0000x reference)
//
#include <hip/hip_runtime.h>
#include <hip/hip_bf16.h>

#define S_LEN 4096
#define HID   512
#define HD    128
#define LOG2_GAMMA (-0.0458036933f)   // log2(0.96875)

typedef short bf16x8 __attribute__((ext_vector_type(8)));
typedef float f32x4  __attribute__((ext_vector_type(4)));
typedef unsigned short u16;

static __device__ __forceinline__ u16 f2bf(float f) {
    union { float f; unsigned u; } v; v.f = f;
    unsigned r = (v.u + 0x7fffu + ((v.u >> 16) & 1u)) >> 16;  // RNE
    return (u16)r;
}

static __device__ __forceinline__ unsigned pk2(float lo, float hi) {
    __hip_bfloat162 h = __float22bfloat162_rn(make_float2(lo, hi));
    union { __hip_bfloat162 h; unsigned u; } c; c.h = h; return c.u;
}
static __device__ __forceinline__ bf16x8 pack8(float4 a, float4 b) {
    union { unsigned u[4]; bf16x8 v; } r;
    r.u[0] = pk2(a.x, a.y); r.u[1] = pk2(a.z, a.w);
    r.u[2] = pk2(b.x, b.y); r.u[3] = pk2(b.z, b.w);
    return r.v;
}

// async global->LDS, 16B per lane; LDS dest = wave-uniform base + lane*16
static __device__ __forceinline__ void gload16(const void* g, void* l) {
    __builtin_amdgcn_global_load_lds(
        (const __attribute__((address_space(1))) unsigned*)g,
        (__attribute__((address_space(3))) unsigned*)l, 16, 0, 0);
}

// ---------------- prep: xpos tables (blocks 0..1023) + weight transpose (1024..1791)
__global__ __launch_bounds__(256) void prep_kernel(const float* __restrict__ WQ,
                                                   const float* __restrict__ WK,
                                                   const float* __restrict__ WV,
                                                   u16* __restrict__ Wt,
                                                   float2* __restrict__ tabQ,
                                                   float2* __restrict__ tabK) {
    if (blockIdx.x < 1024) {
        int idx = blockIdx.x * 256 + threadIdx.x;      // 4096*64 items
        int n = idx >> 6, i = idx & 63;
        float base  = (2.0f * i + 51.2f) * (1.0f / 179.2f);   // (2i+0.4d)/(1.4d), d=128
        float power = (float)n * (1.0f / 512.0f);
        float scale = exp2f(power * log2f(base));
        float inv_freq = exp2f(-(float)i * (13.287712379549449f / 64.0f)); // 10000^(-i/64)
        float theta = (float)n * inv_freq;
        float s, c;
        sincosf(theta, &s, &c);
        tabQ[idx] = make_float2(c * scale, s * scale);
        float is = 1.0f / scale;
        tabK[idx] = make_float2(c * is, s * is);
    } else {
        int idx = (blockIdx.x - 1024) * 256 + threadIdx.x;   // 3*128*512 items
        int w = idx >> 16;
        int rem = idx & 65535;
        int c = rem >> 9, k = rem & 511;
        const float* src = (w == 0) ? WQ : (w == 1) ? WK : WV;
        Wt[idx] = f2bf(src[k * HD + c]);
    }
}

// ---------------- proj v7 (R7-verbatim): single launch, staged BK=32, fused Q|(K+V) -
__global__ __launch_bounds__(256) void proj_kernel(const float* __restrict__ X,
                                                   const float* __restrict__ Mem,
                                                   const u16* __restrict__ Wt,
                                                   const float2* __restrict__ tabQ,
                                                   const float2* __restrict__ tabK,
                                                   u16* __restrict__ Qo,
                                                   u16* __restrict__ Ko,
                                                   u16* __restrict__ Vt) {
    __shared__ __align__(16) float A_lds[2][2048];      // 2 x 8KB
    __shared__ __align__(16) u16   B_lds[2][2][4096];   // 2 bufs x 2 mats x 8KB
    const int tid  = threadIdx.x;
    const int wave = tid >> 6, lane = tid & 63;
    const int l15  = lane & 15, quad = lane >> 4;
    const int rt_base = blockIdx.x * 64;

    if (blockIdx.y == 0) {
        // ------------------------------ Q from X ------------------------------
        auto stage = [&](int ch, int p) {
            const int kc0 = ch * 32;
#pragma unroll
            for (int i = 0; i < 2; ++i) {
                int L = i * 256 + tid;
                int row = L >> 3;
                int s = (L & 7) ^ (row & 7);
                gload16(X + (size_t)(rt_base + row) * HID + kc0 + s * 4,
                        &A_lds[p][(i * 256 + wave * 64) * 4]);
            }
#pragma unroll
            for (int i = 0; i < 2; ++i) {
                int L = i * 256 + tid;
                int col = L >> 2;
                int s = (L & 3) ^ ((col >> 1) & 3);
                gload16(Wt + (size_t)col * HID + kc0 + s * 8,
                        &B_lds[p][0][(i * 256 + wave * 64) * 8]);
            }
        };

        f32x4 acc[8];
#pragma unroll
        for (int ct = 0; ct < 8; ++ct) acc[ct] = (f32x4){0.f, 0.f, 0.f, 0.f};

        stage(0, 0);
        for (int ch = 0; ch < 16; ++ch) {
            const int p = ch & 1;
            __syncthreads();
            if (ch < 15) stage(ch + 1, p ^ 1);
            const int arow = wave * 16 + l15;
            float4 af0 = *(const float4*)&A_lds[p][(arow * 8 + ((quad * 2    ) ^ (l15 & 7))) * 4];
            float4 af1 = *(const float4*)&A_lds[p][(arow * 8 + ((quad * 2 + 1) ^ (l15 & 7))) * 4];
            bf16x8 a = pack8(af0, af1);
#pragma unroll
            for (int ct = 0; ct < 8; ++ct) {
                const int bu = (ct * 16 + l15) * 4 + (quad ^ ((l15 >> 1) & 3));
                bf16x8 b0 = *(const bf16x8*)&B_lds[p][0][bu * 8];
                acc[ct] = __builtin_amdgcn_mfma_f32_16x16x32_bf16(a, b0, acc[ct], 0, 0, 0);
            }
        }

        // Q xpos epilogue (table)
#pragma unroll
        for (int ct = 0; ct < 8; ++ct) {
            int j = ct * 16 + l15;
            int i = j >> 1;
            float sgn = (j & 1) ? 1.0f : -1.0f;
#pragma unroll
            for (int r = 0; r < 4; ++r) {
                int t = rt_base + wave * 16 + quad * 4 + r;
                int n = t & 4095;
                float2 cs = tabQ[n * 64 + i];
                float v = acc[ct][r];
                float partner = __shfl_xor(v, 1, 64);
                Qo[(size_t)t * HD + j] = f2bf(v * cs.x + sgn * partner * cs.y);
            }
        }
    } else {
        // --------------------------- K and V from Mem -------------------------
        const u16* WK_ = Wt + 65536;
        const u16* WV_ = Wt + 131072;

        auto stage = [&](int ch, int p) {
            const int kc0 = ch * 32;
#pragma unroll
            for (int i = 0; i < 2; ++i) {
                int L = i * 256 + tid;
                int row = L >> 3;
                int s = (L & 7) ^ (row & 7);
                gload16(Mem + (size_t)(rt_base + row) * HID + kc0 + s * 4,
                        &A_lds[p][(i * 256 + wave * 64) * 4]);
            }
#pragma unroll
            for (int i = 0; i < 2; ++i) {
                int L = i * 256 + tid;
                int col = L >> 2;
                int s = (L & 3) ^ ((col >> 1) & 3);
                gload16(WK_ + (size_t)col * HID + kc0 + s * 8,
                        &B_lds[p][0][(i * 256 + wave * 64) * 8]);
            }
#pragma unroll
            for (int i = 0; i < 2; ++i) {
                int L = i * 256 + tid;
                int col = L >> 2;
                int s = (L & 3) ^ ((col >> 1) & 3);
                gload16(WV_ + (size_t)col * HID + kc0 + s * 8,
                        &B_lds[p][1][(i * 256 + wave * 64) * 8]);
            }
        };

        f32x4 acc0[8], acc1[8];
#pragma unroll
        for (int ct = 0; ct < 8; ++ct) {
            acc0[ct] = (f32x4){0.f, 0.f, 0.f, 0.f};
            acc1[ct] = (f32x4){0.f, 0.f, 0.f, 0.f};
        }

        stage(0, 0);
        for (int ch = 0; ch < 16; ++ch) {
            const int p = ch & 1;
            __syncthreads();
            if (ch < 15) stage(ch + 1, p ^ 1);
            const int arow = wave * 16 + l15;
            float4 af0 = *(const float4*)&A_lds[p][(arow * 8 + ((quad * 2    ) ^ (l15 & 7))) * 4];
            float4 af1 = *(const float4*)&A_lds[p][(arow * 8 + ((quad * 2 + 1) ^ (l15 & 7))) * 4];
            bf16x8 a = pack8(af0, af1);
#pragma unroll
            for (int ct = 0; ct < 8; ++ct) {
                const int bu = (ct * 16 + l15) * 4 + (quad ^ ((l15 >> 1) & 3));
                bf16x8 b0 = *(const bf16x8*)&B_lds[p][0][bu * 8];
                bf16x8 b1 = *(const bf16x8*)&B_lds[p][1][bu * 8];
                acc0[ct] = __builtin_amdgcn_mfma_f32_16x16x32_bf16(a, b0, acc0[ct], 0, 0, 0);
                acc1[ct] = __builtin_amdgcn_mfma_f32_16x16x32_bf16(a, b1, acc1[ct], 0, 0, 0);
            }
        }

        // K xpos epilogue (table)
#pragma unroll
        for (int ct = 0; ct < 8; ++ct) {
            int j = ct * 16 + l15;
            int i = j >> 1;
            float sgn = (j & 1) ? 1.0f : -1.0f;
#pragma unroll
            for (int r = 0; r < 4; ++r) {
                int t = rt_base + wave * 16 + quad * 4 + r;
                int n = t & 4095;
                float2 cs = tabK[n * 64 + i];
                float v = acc0[ct][r];
                float partner = __shfl_xor(v, 1, 64);
                Ko[(size_t)t * HD + j] = f2bf(v * cs.x + sgn * partner * cs.y);
            }
        }

        // V transpose via LDS scratch (reuses B_lds: 20KB <= 32KB) -> Vt[b][h][s]
        u16* Vs = (u16*)&B_lds[0][0][0];
        __syncthreads();                 // all waves done reading K-loop LDS
#pragma unroll
        for (int ct = 0; ct < 8; ++ct) {
            int col = ct * 16 + l15;
#pragma unroll
            for (int r = 0; r < 4; ++r)
                Vs[col * 80 + wave * 16 + quad * 4 + r] = f2bf(acc1[ct][r]);
        }
        __syncthreads();
        int b = rt_base >> 12, sb = rt_base & 4095;
        int h = tid >> 1, sof = (tid & 1) * 32;
#pragma unroll
        for (int pp = 0; pp < 4; ++pp) {
            bf16x8 v = *(const bf16x8*)&Vs[h * 80 + sof + pp * 8];
            *(bf16x8*)(Vt + (size_t)(b * 128 + h) * S_LEN + sb + sof + pp * 8) = v;
        }
    }
}

// ---------------- windowed retention v6: parity-split over kv, zero QK duplication --
// grid 512 (b*128 + qtile32); block 256 (4 waves). wave: rt = w&1 (16 q-rows),
// par = w>>1 (kv-tile parity). Each wave: QK^T on its parity's 64-kv tiles for its
// 16 rows, then PV over ALL 128 head cols (partial O). K staged in 128-kv
// super-tiles (2 parity tiles / barrier, dbuf, 64KB). P wave-private in LDS
// (xor-swizzled [16][64] fp32). One cross-parity O reduction at the end.
// MFMA issue per 32 rows x 128 kv: 128 (was 192); barriers halved; window 384
// (gamma^385 ~ 4.9e-6, tail error ~1e-7 << bf16-rounding absmax 1.2e-4).
__global__ __launch_bounds__(256, 2) void ret_kernel(const u16* __restrict__ Qb,
                                                     const u16* __restrict__ Kb,
                                                     const u16* __restrict__ Vt,
                                                     float* __restrict__ out) {
    __shared__ __align__(16) u16   K_lds[2][16384];     // 2 ph x (128 kv x 128 hd) = 64KB
    __shared__ __align__(16) float P_lds[4][16][64];    // per-wave 16x64 fp32, swizzled
    const int tid  = threadIdx.x;
    const int wave = tid >> 6, lane = tid & 63;
    const int l15  = lane & 15, quad = lane >> 4;
    const int b   = blockIdx.x >> 7;
    const int qt  = (blockIdx.x & 127) * 32;
    const int rt  = wave & 1;          // q row-tile (16 rows)
    const int par = wave >> 1;         // kv 64-tile parity within a 128 super-tile
    const int qw  = qt + rt * 16;

    int kv_lo = (qt - 384) & ~127;     // 128-aligned window start
    if (kv_lo < 0) kv_lo = 0;
    const int nst = (qt + 32 - kv_lo + 127) >> 7;   // <= 4 super-tiles

    auto stageK = [&](int st, int ph) {
        const int kv0 = kv_lo + st * 128;
#pragma unroll
        for (int i = 0; i < 8; ++i) {
            int u = i * 256 + tid;
            int kvr = u >> 4;                       // 0..127 within super-tile
            int s = (u & 15) ^ (kvr & 15);
            gload16(Kb + (size_t)(b * S_LEN + kv0 + kvr) * HD + s * 8,
                    &K_lds[ph][(i * 256 + wave * 64) * 8]);
        }
    };

    const size_t tq = (size_t)(b * S_LEN + qw + l15);
    bf16x8 qfrag[4];
#pragma unroll
    for (int kc = 0; kc < 4; ++kc)
        qfrag[kc] = *(const bf16x8*)(Qb + tq * HD + kc * 32 + quad * 8);

    const u16* vbase = Vt + (size_t)b * HD * S_LEN;

    f32x4 acco[8];
#pragma unroll
    for (int hc = 0; hc < 8; ++hc) acco[hc] = (f32x4){0.f, 0.f, 0.f, 0.f};

    stageK(0, 0);
    for (int st = 0; st < nst; ++st) {
        const int ph = st & 1;
        __syncthreads();               // super-tile st staged; other buf free
        if (st + 1 < nst) stageK(st + 1, ph ^ 1);

        const int kv0 = kv_lo + st * 128 + par * 64;   // this wave's 64-kv tile
        if (kv0 <= qw + 15) {          // tile not entirely in the causal future
            // V prefetch: all 128 head cols for this wave's kv tile
            bf16x8 vf[8][2];
#pragma unroll
            for (int hc = 0; hc < 8; ++hc) {
                const u16* vb = vbase + (size_t)(hc * 16 + l15) * S_LEN + kv0 + quad * 8;
                vf[hc][0] = *(const bf16x8*)vb;
                vf[hc][1] = *(const bf16x8*)(vb + 32);
            }

            // ---- S = Q K^T (16 rows x 64 kv, unique per wave) ----
            f32x4 accs[4];
#pragma unroll
            for (int ct = 0; ct < 4; ++ct) accs[ct] = (f32x4){0.f, 0.f, 0.f, 0.f};
#pragma unroll
            for (int ct = 0; ct < 4; ++ct) {
                const int kvr = par * 64 + ct * 16 + l15;   // row in super-tile
#pragma unroll
                for (int kc = 0; kc < 4; ++kc) {
                    bf16x8 kf = *(const bf16x8*)
                        &K_lds[ph][(kvr * 16 + ((kc * 4 + quad) ^ (kvr & 15))) * 8];
                    accs[ct] = __builtin_amdgcn_mfma_f32_16x16x32_bf16(qfrag[kc], kf, accs[ct], 0, 0, 0);
                }
            }
            // ---- decay + causal mask -> wave-private swizzled P (no barrier) ----
#pragma unroll
            for (int ct = 0; ct < 4; ++ct) {
                int kvi = kv0 + ct * 16 + l15;
#pragma unroll
                for (int r = 0; r < 4; ++r) {
                    int d = (qw + quad * 4 + r) - kvi;
                    float w = exp2f((float)d * LOG2_GAMMA);
                    int row = quad * 4 + r, col = ct * 16 + l15;
                    P_lds[wave][row][col ^ ((row & 7) << 2)] = (d >= 0) ? accs[ct][r] * w : 0.0f;
                }
            }
            // ---- P as A-fragments (within-wave lgkmcnt only) ----
            int sw = (l15 & 7) << 2;
            float4 p00 = *(const float4*)&P_lds[wave][l15][(quad * 8    ) ^ sw];
            float4 p01 = *(const float4*)&P_lds[wave][l15][(quad * 8 + 4) ^ sw];
            bf16x8 pa0 = pack8(p00, p01);
            // second k-slice (kv 32..63)
            float4 p10 = *(const float4*)&P_lds[wave][l15][(32 + quad * 8    ) ^ sw];
            float4 p11 = *(const float4*)&P_lds[wave][l15][(32 + quad * 8 + 4) ^ sw];
            bf16x8 pa1 = pack8(p10, p11);
            // ---- O(partial) += P V over all 128 head cols ----
#pragma unroll
            for (int hc = 0; hc < 8; ++hc) {
                acco[hc] = __builtin_amdgcn_mfma_f32_16x16x32_bf16(pa0, vf[hc][0], acco[hc], 0, 0, 0);
                acco[hc] = __builtin_amdgcn_mfma_f32_16x16x32_bf16(pa1, vf[hc][1], acco[hc], 0, 0, 0);
            }
        }
    }

    // ---- cross-parity O reduction via LDS (K_lds is free now) ----
    __syncthreads();                   // all K_lds reads done
    float* red = (float*)&K_lds[0][0]; // 2 x 16 x 128 fp32 = 16KB
    if (par) {
#pragma unroll
        for (int hc = 0; hc < 8; ++hc)
#pragma unroll
            for (int r = 0; r < 4; ++r)
                red[(rt * 16 + quad * 4 + r) * 128 + hc * 16 + l15] = acco[hc][r];
    }
    __syncthreads();
    if (!par) {
#pragma unroll
        for (int hc = 0; hc < 8; ++hc)
#pragma unroll
            for (int r = 0; r < 4; ++r)
                out[(size_t)(b * S_LEN + qw + quad * 4 + r) * HD + hc * 16 + l15]
                    = acco[hc][r] + red[(rt * 16 + quad * 4 + r) * 128 + hc * 16 + l15];
    }
}

extern "C" void kernel_launch(void* const* d_in, const int* in_sizes, int n_in,
                              void* d_out, int out_size, void* d_ws, size_t ws_size,
                              hipStream_t stream) {
    const float* X   = (const float*)d_in[0];
    const float* Mem = (const float*)d_in[1];
    const float* WQ  = (const float*)d_in[2];
    const float* WK  = (const float*)d_in[3];
    const float* WV  = (const float*)d_in[4];
    float* out = (float*)d_out;

    char* ws = (char*)d_ws;
    u16*    Qb   = (u16*)(ws);                         // 4 MB  bf16 [16384][128]
    u16*    Kb   = (u16*)(ws + ((size_t)4 << 20));     // 4 MB
    u16*    Vt   = (u16*)(ws + ((size_t)8 << 20));     // 4 MB  bf16 [4][128][4096]
    u16*    Wt   = (u16*)(ws + ((size_t)12 << 20));    // 384 KB bf16 [3][128][512]
    float2* tabQ = (float2*)(ws + ((size_t)13 << 20)); // 2 MB
    float2* tabK = (float2*)(ws + ((size_t)15 << 20)); // 2 MB

    prep_kernel<<<dim3(1792), dim3(256), 0, stream>>>(WQ, WK, WV, Wt, tabQ, tabK);
    proj_kernel<<<dim3(256, 2), dim3(256), 0, stream>>>(X, Mem, Wt, tabQ, tabK, Qb, Kb, Vt);
    ret_kernel<<<dim3(512), dim3(256), 0, stream>>>(Qb, Kb, Vt, out);
}